// Round 4
// baseline (14891.174 us; speedup 1.0000x reference)
//
#include <hip/hip_runtime.h>

// (T,B,I,H) = (1024, 64, 512, 512)
#define T_STEPS 1024
#define BATCH   64
#define IN_F    512
#define HID     512
#define G3      1536
#define M_ROWS  (T_STEPS * BATCH)

#define NSLICE  16
#define NGROUP  16
#define SPG     4
#define HB_U64  (2 * NGROUP * SPG * 256)   // one arena: ping-pong u64 entries
#define ZERO_U64 (2 * HB_U64 + 512)        // arenas A+L plus ctrl area

typedef _Float16 v8h  __attribute__((ext_vector_type(8)));
typedef float    v4f  __attribute__((ext_vector_type(4)));

// ---------------------------------------------------------------------------
// gx = x * w_ih^T + b_ih -> f16 [65536][1536]   (unchanged, passing)
// ---------------------------------------------------------------------------
#define BM 64
#define BN 128
#define BK 32
#define LDP 40

__global__ __launch_bounds__(256) void gemm_gx(
    const float* __restrict__ X, const float* __restrict__ W,
    const float* __restrict__ bias, _Float16* __restrict__ C) {
  __shared__ _Float16 As[BM][LDP];
  __shared__ _Float16 Bs[BN][LDP];
  const int tid  = threadIdx.x;
  const int lane = tid & 63;
  const int wave = tid >> 6;
  const int m0 = blockIdx.y * BM;
  const int n0 = blockIdx.x * BN;

  v4f acc[8];
#pragma unroll
  for (int i = 0; i < 8; ++i) acc[i] = (v4f){0.f, 0.f, 0.f, 0.f};

  const int srow  = tid >> 2;
  const int kpart = (tid & 3) * 8;
  const int fr = lane & 15;
  const int ko = (lane >> 4) * 8;

  for (int kc = 0; kc < IN_F; kc += BK) {
    {
      const float* s = X + (size_t)(m0 + srow) * IN_F + kc + kpart;
      float4 a = *(const float4*)s;
      float4 b = *(const float4*)(s + 4);
      v8h o = {(_Float16)a.x, (_Float16)a.y, (_Float16)a.z, (_Float16)a.w,
               (_Float16)b.x, (_Float16)b.y, (_Float16)b.z, (_Float16)b.w};
      *(v8h*)&As[srow][kpart] = o;
    }
#pragma unroll
    for (int r = 0; r < 2; ++r) {
      const float* s = W + (size_t)(n0 + r * 64 + srow) * IN_F + kc + kpart;
      float4 a = *(const float4*)s;
      float4 b = *(const float4*)(s + 4);
      v8h o = {(_Float16)a.x, (_Float16)a.y, (_Float16)a.z, (_Float16)a.w,
               (_Float16)b.x, (_Float16)b.y, (_Float16)b.z, (_Float16)b.w};
      *(v8h*)&Bs[r * 64 + srow][kpart] = o;
    }
    __syncthreads();
    v8h af = *(const v8h*)&As[wave * 16 + fr][ko];
#pragma unroll
    for (int nt = 0; nt < 8; ++nt) {
      v8h bf = *(const v8h*)&Bs[nt * 16 + fr][ko];
      acc[nt] = __builtin_amdgcn_mfma_f32_16x16x32_f16(af, bf, acc[nt], 0, 0, 0);
    }
    __syncthreads();
  }

  const int rq = lane >> 4;
#pragma unroll
  for (int nt = 0; nt < 8; ++nt) {
    const int gcol = n0 + nt * 16 + fr;
    const float bv = bias[gcol];
#pragma unroll
    for (int r = 0; r < 4; ++r) {
      const int grow = m0 + wave * 16 + rq * 4 + r;
      C[(size_t)grow * G3 + gcol] = (_Float16)(acc[nt][r] + bv);
    }
  }
}

__global__ void zero_hbuf(unsigned long long* h) {
  const int i = blockIdx.x * 256 + threadIdx.x;
  if (i < ZERO_U64) h[i] = 0ull;
}

// Zero-pad out rows with t >= len[b] (scan does not write them).
__global__ __launch_bounds__(256) void zero_out_tail(const int* __restrict__ lens,
                                                     float* __restrict__ out) {
  __shared__ int slen[BATCH];
  if (threadIdx.x < BATCH) slen[threadIdx.x] = lens[threadIdx.x];
  __syncthreads();
  for (int row = blockIdx.x; row < T_STEPS * BATCH; row += gridDim.x) {
    const int t = row >> 6;
    const int b = row & 63;
    if (t < slen[b]) continue;
    float2* dst = (float2*)(out + (size_t)row * HID);
    dst[threadIdx.x] = make_float2(0.f, 0.f);
  }
}

// ---------------------------------------------------------------------------
// XCD-local persistent-weight GRU scan, barrier-free self-placement.
// 256 WGs; tid0 reads HW_REG_XCC_ID and claims slot xcd*32+k (per-XCD
// atomicAdd); overflow WGs CAS-scan free slots (terminates by pigeonhole).
// slot -> (grp = slot>>4, slice = slot&15), so XCD x natively hosts groups
// {2x,2x+1}. Group members publish their XCD to xtab[slot] (write-once) and
// poll the 15 peers; verdict local = all 16 XCDs equal (deterministic,
// unanimous). Local groups exchange through their XCD L2: publish = plain
// store to hbufL (write-through L1->L2) AND v2 agent store to hbufA; readers
// poll hbufL with workgroup-scope fetch_add(+0) (atomics execute at L2 =>
// same-XCD fresh). Sticky per-thread fallback after 6000 poll rounds switches
// to hbufA agent polling (always correct since writers dual-publish).
// Non-local groups run the v2-proven agent protocol unchanged.
// ---------------------------------------------------------------------------
#define GETREG_XCC_ID 63508   // s_getreg: hwreg 20 (XCC_ID), offset 0, width 32

__global__ __launch_bounds__(192, 2) void gru_scan6(
    const _Float16* __restrict__ gx, const float* __restrict__ whh,
    const int* __restrict__ lens, const float* __restrict__ bhh,
    float* __restrict__ out, unsigned long long* hb) {
  const int tid  = threadIdx.x;
  const int lane = tid & 63;
  const int w    = tid >> 6;    // wave = gate (0:r 1:z 2:n)

  unsigned long long* hbufA = hb;                 // agent/MALL arena (v2)
  unsigned long long* hbufL = hb + HB_U64;        // XCD-L2 arena
  unsigned* ctrl = (unsigned*)(hb + 2 * HB_U64);
  unsigned* cnt   = ctrl;        // [8]  per-XCD claim counters
  unsigned* claim = ctrl + 8;    // [256] slot claim table
  unsigned* xtab  = ctrl + 264;  // [256] slot -> xcd+1

  __shared__ __align__(16) _Float16 h16[16 * 520];  // +8 pad
  __shared__ __align__(16) float ghl[3 * 32 * 4];   // [gate][col][seq]
  __shared__ int sres[2];                           // {slot, lflag}

  // ---------------- barrier-free self-placement (tid 0) ----------------
  if (tid == 0) {
    const int xcd = (int)(__builtin_amdgcn_s_getreg(GETREG_XCC_ID) & 7u);
    const unsigned k = __hip_atomic_fetch_add(&cnt[xcd], 1u,
                          __ATOMIC_RELAXED, __HIP_MEMORY_SCOPE_AGENT);
    int slot = -1;
    if (k < 32u) {
      slot = xcd * 32 + (int)k;
      __hip_atomic_store(&claim[slot], 1u, __ATOMIC_RELAXED,
                         __HIP_MEMORY_SCOPE_AGENT);
    } else {
      int i = (xcd * 32) & 255;
      const int start = i;
      while (slot < 0) {
        if (__hip_atomic_load(&claim[i], __ATOMIC_RELAXED,
                              __HIP_MEMORY_SCOPE_AGENT) == 0u) {
          unsigned exp = 0u;
          if (__hip_atomic_compare_exchange_strong(&claim[i], &exp, 1u,
                  __ATOMIC_RELAXED, __ATOMIC_RELAXED,
                  __HIP_MEMORY_SCOPE_AGENT)) { slot = i; break; }
        }
        i = (i + 1) & 255;
        if (i == start) __builtin_amdgcn_s_sleep(2);
      }
    }
    __hip_atomic_store(&xtab[slot], (unsigned)(xcd + 1), __ATOMIC_RELAXED,
                       __HIP_MEMORY_SCOPE_AGENT);
    const int g = slot >> 4;
    unsigned v0 = 0u; int same = 1;
    for (int s = 0; s < 16; ++s) {
      unsigned v;
      for (;;) {
        v = __hip_atomic_load(&xtab[g * 16 + s], __ATOMIC_RELAXED,
                              __HIP_MEMORY_SCOPE_AGENT);
        if (v) break;
        __builtin_amdgcn_s_sleep(2);
      }
      if (s == 0) v0 = v; else same &= (v == v0) ? 1 : 0;
    }
    sres[0] = slot;
    sres[1] = same;
  }
  __syncthreads();
  const int slice = sres[0] & 15;
  const int grp   = sres[0] >> 4;
  const int lflag = sres[1];
  const int b0    = grp * SPG;

  for (int i = tid; i < 16 * 520 / 2; i += 192) ((unsigned*)h16)[i] = 0u;

  // ---- persistent weight B-frags: wave w, rows w*512 + slice*32 + [0,32)
  v8h bw0[16], bw1[16];
  {
    const int r15 = lane & 15;
    const int k8  = (lane >> 4) * 8;
    const float* p0 = whh + (size_t)(w * 512 + slice * 32 + r15) * HID + k8;
    const float* p1 = p0 + 16 * HID;
#pragma unroll
    for (int kt = 0; kt < 16; ++kt) {
      float4 a = *(const float4*)(p0 + kt * 32);
      float4 b = *(const float4*)(p0 + kt * 32 + 4);
      bw0[kt] = (v8h){(_Float16)a.x, (_Float16)a.y, (_Float16)a.z, (_Float16)a.w,
                      (_Float16)b.x, (_Float16)b.y, (_Float16)b.z, (_Float16)b.w};
      float4 c = *(const float4*)(p1 + kt * 32);
      float4 d = *(const float4*)(p1 + kt * 32 + 4);
      bw1[kt] = (v8h){(_Float16)c.x, (_Float16)c.y, (_Float16)c.z, (_Float16)c.w,
                      (_Float16)d.x, (_Float16)d.y, (_Float16)d.z, (_Float16)d.w};
    }
  }

  // ---- epilogue thread state: tid<64 owns (seq = tid>>4, cols ec0,ec0+1)
  const int eseq = tid >> 4;
  const int ec0  = (tid & 15) * 2;
  const int ej   = slice * 32 + ec0;
  float hr0 = 0.f, hr1 = 0.f;
  float br0 = 0, br1 = 0, bz0 = 0, bz1 = 0, bn0 = 0, bn1 = 0;
  int mylen = 0;
  unsigned pg0 = 0, pg1 = 0, pg2 = 0;
  if (tid < 64) {
    br0 = bhh[ej];        br1 = bhh[ej + 1];
    bz0 = bhh[ej + 512];  bz1 = bhh[ej + 513];
    bn0 = bhh[ej + 1024]; bn1 = bhh[ej + 1025];
    mylen = lens[b0 + eseq];
    const _Float16* gxr = gx + ((size_t)0 * BATCH + b0 + eseq) * G3 + ej;
    pg0 = *(const unsigned*)gxr;
    pg1 = *(const unsigned*)(gxr + 512);
    pg2 = *(const unsigned*)(gxr + 1024);
  }
  const int glen = max(max(lens[b0], lens[b0 + 1]), max(lens[b0 + 2], lens[b0 + 3]));
  __syncthreads();

  const int arow = lane & 15;
  const int ak   = (lane >> 4) * 8;
  const _Float16* hbase = &h16[arow * 520 + ak];

  // pull-set indices for this thread (<=6 of the group's 1024 u64s)
  int ii[6]; int nn = 0;
  for (int i = tid; i < SPG * 256; i += 192) { ii[nn] = i; ++nn; }

  int llive = lflag;   // sticky per-thread: 1 = poll own-XCD L2 arena

  for (int t = 0; t < glen; ++t) {
    // ---- matvec: gh[seq][row] for this wave's 32 rows
    v4f acc0 = (v4f){0.f, 0.f, 0.f, 0.f};
    v4f acc1 = (v4f){0.f, 0.f, 0.f, 0.f};
#pragma unroll
    for (int kt = 0; kt < 16; ++kt) {
      v8h af = *(const v8h*)(hbase + kt * 32);
      acc0 = __builtin_amdgcn_mfma_f32_16x16x32_f16(af, bw0[kt], acc0, 0, 0, 0);
      acc1 = __builtin_amdgcn_mfma_f32_16x16x32_f16(af, bw1[kt], acc1, 0, 0, 0);
    }
    if (lane < 16) {  // lanes 0..15: reg p = seq p, col n = lane
      *(v4f*)&ghl[(w * 32 + lane) * 4]      = acc0;
      *(v4f*)&ghl[(w * 32 + 16 + lane) * 4] = acc1;
    }
    __syncthreads();   // ghl ready; all h16 MFMA reads done

    if (tid < 64) {
      const float ar0 = ghl[(0 * 32 + ec0) * 4 + eseq], ar1 = ghl[(0 * 32 + ec0 + 1) * 4 + eseq];
      const float az0 = ghl[(1 * 32 + ec0) * 4 + eseq], az1 = ghl[(1 * 32 + ec0 + 1) * 4 + eseq];
      const float an0 = ghl[(2 * 32 + ec0) * 4 + eseq], an1 = ghl[(2 * 32 + ec0 + 1) * 4 + eseq];
      union { unsigned u; _Float16 h[2]; } g0, g1, g2, pk;
      g0.u = pg0; g1.u = pg1; g2.u = pg2;
      const bool act = (t < mylen);
      if (act) {
        const float r0 = 1.f / (1.f + __expf(-((float)g0.h[0] + ar0 + br0)));
        const float z0 = 1.f / (1.f + __expf(-((float)g1.h[0] + az0 + bz0)));
        const float p0 = (float)g2.h[0] + r0 * (an0 + bn0);
        const float n0v = 1.f - 2.f / (__expf(2.f * p0) + 1.f);
        hr0 = (1.f - z0) * n0v + z0 * hr0;
        const float r1 = 1.f / (1.f + __expf(-((float)g0.h[1] + ar1 + br1)));
        const float z1 = 1.f / (1.f + __expf(-((float)g1.h[1] + az1 + bz1)));
        const float p1 = (float)g2.h[1] + r1 * (an1 + bn1);
        const float n1v = 1.f - 2.f / (__expf(2.f * p1) + 1.f);
        hr1 = (1.f - z1) * n1v + z1 * hr1;
      }
      // publish [tag | h1 | h0] first (peers' critical path)
      pk.h[0] = (_Float16)hr0; pk.h[1] = (_Float16)hr1;
      const unsigned long long pv =
          ((unsigned long long)(unsigned)(t + 1) << 32) | pk.u;
      const size_t di = (size_t)((((t + 1) & 1) * NGROUP + grp) * SPG + eseq) * 256
                        + slice * 16 + (tid & 15);
      if (lflag)   // dual publish: own-XCD L2 copy + MALL safety copy
        __hip_atomic_store(hbufL + di, pv, __ATOMIC_RELAXED,
                           __HIP_MEMORY_SCOPE_WORKGROUP);
      __hip_atomic_store(hbufA + di, pv, __ATOMIC_RELAXED,
                         __HIP_MEMORY_SCOPE_AGENT);
      if (act) {
        float* o = out + (size_t)t * (BATCH * HID) + (size_t)(b0 + eseq) * HID + ej;
        o[0] = hr0; o[1] = hr1;
      }
      // prefetch gx for next step (off critical path; clamp in-bounds)
      const int tn = (t + 1 < glen) ? t + 1 : t;
      const _Float16* gxr = gx + ((size_t)tn * BATCH + b0 + eseq) * G3 + ej;
      pg0 = *(const unsigned*)gxr;
      pg1 = *(const unsigned*)(gxr + 512);
      pg2 = *(const unsigned*)(gxr + 1024);
    }

    // ---- tagged pull for step t+1: poll until tag >= t+1
    {
      const size_t aoff = (size_t)(((t + 1) & 1) * NGROUP + grp) * (SPG * 256);
      const unsigned want = (unsigned)(t + 1);
      unsigned long long got[6];
      unsigned pend = (1u << nn) - 1u;
      if (llive) {
        // local: L2-executed atomic reads of own-XCD arena (fresh, fast)
        unsigned long long* srcL = hbufL + aoff;
        int rounds = 0;
        while (pend) {
#pragma unroll
          for (int j = 0; j < 6; ++j)
            if (j < nn && (pend & (1u << j)))
              got[j] = __hip_atomic_fetch_add(srcL + ii[j], 0ull,
                           __ATOMIC_RELAXED, __HIP_MEMORY_SCOPE_WORKGROUP);
#pragma unroll
          for (int j = 0; j < 6; ++j)
            if (j < nn && (pend & (1u << j)) &&
                (unsigned)(got[j] >> 32) >= want) {
              const int sq = ii[j] >> 8, jj = ii[j] & 255;
              *(unsigned*)&h16[sq * 520 + jj * 2] = (unsigned)got[j];
              pend &= ~(1u << j);
            }
          if (pend) {
            if (++rounds > 6000) { llive = 0; break; }  // sticky fallback
            __builtin_amdgcn_s_sleep(1);
          }
        }
      }
      if (pend) {
        // v2-proven agent-scope protocol (also the sticky-fallback path)
        const unsigned long long* srcA = hbufA + aoff;
        while (pend) {
#pragma unroll
          for (int j = 0; j < 6; ++j)
            if (j < nn && (pend & (1u << j)))
              got[j] = __hip_atomic_load(srcA + ii[j], __ATOMIC_RELAXED,
                                         __HIP_MEMORY_SCOPE_AGENT);
#pragma unroll
          for (int j = 0; j < 6; ++j)
            if (j < nn && (pend & (1u << j)) &&
                (unsigned)(got[j] >> 32) >= want) {
              const int sq = ii[j] >> 8, jj = ii[j] & 255;
              *(unsigned*)&h16[sq * 520 + jj * 2] = (unsigned)got[j];
              pend &= ~(1u << j);
            }
          if (pend) __builtin_amdgcn_s_sleep(1);
        }
      }
    }
    __syncthreads();   // h16 (t+1) ready for next matvec
  }

  if (tid < 64) {
    float* hl = out + (size_t)T_STEPS * BATCH * HID + (size_t)(b0 + eseq) * HID + ej;
    hl[0] = hr0; hl[1] = hr1;
  }
}

// ---------------------------------------------------------------------------
extern "C" void kernel_launch(void* const* d_in, const int* in_sizes, int n_in,
                              void* d_out, int out_size, void* d_ws, size_t ws_size,
                              hipStream_t stream) {
  const float* x    = (const float*)d_in[0];
  const int*   lens = (const int*)d_in[1];
  const float* w_ih = (const float*)d_in[2];
  const float* w_hh = (const float*)d_in[3];
  const float* b_ih = (const float*)d_in[4];
  const float* b_hh = (const float*)d_in[5];
  float* out = (float*)d_out;

  // ws: gx f16 [65536][1536] = 192 MiB | hbufA + hbufL + ctrl
  _Float16* gxbuf = (_Float16*)d_ws;
  unsigned long long* hb = (unsigned long long*)(gxbuf + (size_t)M_ROWS * G3);

  zero_hbuf<<<dim3((ZERO_U64 + 255) / 256), dim3(256), 0, stream>>>(hb);
  zero_out_tail<<<dim3(2048), dim3(256), 0, stream>>>(lens, out);
  gemm_gx<<<dim3(G3 / BN, M_ROWS / BM), dim3(256), 0, stream>>>(x, w_ih, b_ih, gxbuf);
  gru_scan6<<<dim3(NSLICE * NGROUP), dim3(192), 0, stream>>>(
      gxbuf, w_hh, lens, b_hh, out, hb);
}

// Round 5
// 2926.642 us; speedup vs baseline: 5.0881x; 5.0881x over previous
//
#include <hip/hip_runtime.h>

// (T,B,I,H) = (1024, 64, 512, 512)
#define T_STEPS 1024
#define BATCH   64
#define IN_F    512
#define HID     512
#define G3      1536
#define M_ROWS  (T_STEPS * BATCH)

#define NSLICE  16
#define NGROUP  16
#define SPG     4
#define HB_U64  (2 * NGROUP * SPG * 256)   // one arena: ping-pong u64 entries
#define ZERO_U64 (2 * HB_U64 + 512)        // arenas A+L plus xtab/ctrl area

typedef _Float16 v8h  __attribute__((ext_vector_type(8)));
typedef float    v4f  __attribute__((ext_vector_type(4)));

// ---------------------------------------------------------------------------
// gx = x * w_ih^T + b_ih -> f16 [65536][1536]   (unchanged, passing)
// ---------------------------------------------------------------------------
#define BM 64
#define BN 128
#define BK 32
#define LDP 40

__global__ __launch_bounds__(256) void gemm_gx(
    const float* __restrict__ X, const float* __restrict__ W,
    const float* __restrict__ bias, _Float16* __restrict__ C) {
  __shared__ _Float16 As[BM][LDP];
  __shared__ _Float16 Bs[BN][LDP];
  const int tid  = threadIdx.x;
  const int lane = tid & 63;
  const int wave = tid >> 6;
  const int m0 = blockIdx.y * BM;
  const int n0 = blockIdx.x * BN;

  v4f acc[8];
#pragma unroll
  for (int i = 0; i < 8; ++i) acc[i] = (v4f){0.f, 0.f, 0.f, 0.f};

  const int srow  = tid >> 2;
  const int kpart = (tid & 3) * 8;
  const int fr = lane & 15;
  const int ko = (lane >> 4) * 8;

  for (int kc = 0; kc < IN_F; kc += BK) {
    {
      const float* s = X + (size_t)(m0 + srow) * IN_F + kc + kpart;
      float4 a = *(const float4*)s;
      float4 b = *(const float4*)(s + 4);
      v8h o = {(_Float16)a.x, (_Float16)a.y, (_Float16)a.z, (_Float16)a.w,
               (_Float16)b.x, (_Float16)b.y, (_Float16)b.z, (_Float16)b.w};
      *(v8h*)&As[srow][kpart] = o;
    }
#pragma unroll
    for (int r = 0; r < 2; ++r) {
      const float* s = W + (size_t)(n0 + r * 64 + srow) * IN_F + kc + kpart;
      float4 a = *(const float4*)s;
      float4 b = *(const float4*)(s + 4);
      v8h o = {(_Float16)a.x, (_Float16)a.y, (_Float16)a.z, (_Float16)a.w,
               (_Float16)b.x, (_Float16)b.y, (_Float16)b.z, (_Float16)b.w};
      *(v8h*)&Bs[r * 64 + srow][kpart] = o;
    }
    __syncthreads();
    v8h af = *(const v8h*)&As[wave * 16 + fr][ko];
#pragma unroll
    for (int nt = 0; nt < 8; ++nt) {
      v8h bf = *(const v8h*)&Bs[nt * 16 + fr][ko];
      acc[nt] = __builtin_amdgcn_mfma_f32_16x16x32_f16(af, bf, acc[nt], 0, 0, 0);
    }
    __syncthreads();
  }

  const int rq = lane >> 4;
#pragma unroll
  for (int nt = 0; nt < 8; ++nt) {
    const int gcol = n0 + nt * 16 + fr;
    const float bv = bias[gcol];
#pragma unroll
    for (int r = 0; r < 4; ++r) {
      const int grow = m0 + wave * 16 + rq * 4 + r;
      C[(size_t)grow * G3 + gcol] = (_Float16)(acc[nt][r] + bv);
    }
  }
}

__global__ void zero_hbuf(unsigned long long* h) {
  const int i = blockIdx.x * 256 + threadIdx.x;
  if (i < ZERO_U64) h[i] = 0ull;
}

// Zero-pad out rows with t >= len[b] (scan does not write them).
__global__ __launch_bounds__(256) void zero_out_tail(const int* __restrict__ lens,
                                                     float* __restrict__ out) {
  __shared__ int slen[BATCH];
  if (threadIdx.x < BATCH) slen[threadIdx.x] = lens[threadIdx.x];
  __syncthreads();
  for (int row = blockIdx.x; row < T_STEPS * BATCH; row += gridDim.x) {
    const int t = row >> 6;
    const int b = row & 63;
    if (t < slen[b]) continue;
    float2* dst = (float2*)(out + (size_t)row * HID);
    dst[threadIdx.x] = make_float2(0.f, 0.f);
  }
}

// ---------------------------------------------------------------------------
// v2 skeleton + XCD-L2 polling.
// Mapping grp = bid&15 puts group g's 16 slice-WGs at bids == g (mod 16):
// under round-robin dispatch they share XCD g%8. Each WG publishes its real
// XCC_ID to xtab[bid]; tid0 checks unanimity over the group -> lflag.
// Publishers ALWAYS dual-publish: plain store to hbufL (write-through L1 ->
// own L2) + relaxed agent store to hbufA (MALL, v2-proven). Local readers
// poll hbufL with plain `global_load_dwordx2 ... sc0` (L1-bypass, served by
// the shared XCD L2: fresh, pipelined, no RMW). Sticky per-thread fallback
// after 256 empty rounds switches to the v2 agent poll on hbufA forever.
// Exchange format (tag-in-data u64, ping-pong) unchanged from v2.
// ---------------------------------------------------------------------------
#define GETREG_XCC_ID 63508   // s_getreg: hwreg 20 (XCC_ID), offset 0, width 32

__global__ __launch_bounds__(192, 2) void gru_scan7(
    const _Float16* __restrict__ gx, const float* __restrict__ whh,
    const int* __restrict__ lens, const float* __restrict__ bhh,
    float* __restrict__ out, unsigned long long* hb) {
  const int bid   = blockIdx.x;
  const int slice = bid >> 4;
  const int grp   = bid & 15;
  const int b0  = grp * SPG;
  const int tid  = threadIdx.x;
  const int lane = tid & 63;
  const int w    = tid >> 6;    // wave = gate (0:r 1:z 2:n)

  unsigned long long* hbufA = hb;                 // agent/MALL arena (v2)
  unsigned long long* hbufL = hb + HB_U64;        // XCD-L2 arena
  unsigned* xtab = (unsigned*)(hb + 2 * HB_U64);  // [256] bid -> xcd+1

  __shared__ __align__(16) _Float16 h16[16 * 520];  // +8 pad
  __shared__ __align__(16) float ghl[3 * 32 * 4];   // [gate][col][seq]
  __shared__ int sres[1];                           // locality verdict

  // ---------------- locality probe (tid 0), bounded, no barriers ----------
  if (tid == 0) {
    const int xcd = (int)(__builtin_amdgcn_s_getreg(GETREG_XCC_ID) & 7u);
    __hip_atomic_store(&xtab[bid], (unsigned)(xcd + 1), __ATOMIC_RELAXED,
                       __HIP_MEMORY_SCOPE_AGENT);
    unsigned v0 = 0u; int ok = 1;
    for (int s = 0; s < 16 && ok; ++s) {
      unsigned v = 0u;
      for (int r = 0; r < 20000; ++r) {
        v = __hip_atomic_load(&xtab[s * 16 + grp], __ATOMIC_RELAXED,
                              __HIP_MEMORY_SCOPE_AGENT);
        if (v) break;
        __builtin_amdgcn_s_sleep(2);
      }
      if (!v) { ok = 0; break; }
      if (s == 0) v0 = v; else ok = (v == v0) ? ok : 0;
    }
    sres[0] = ok;
  }

  for (int i = tid; i < 16 * 520 / 2; i += 192) ((unsigned*)h16)[i] = 0u;

  // ---- persistent weight B-frags: wave w, rows w*512 + slice*32 + [0,32)
  v8h bw0[16], bw1[16];
  {
    const int r15 = lane & 15;
    const int k8  = (lane >> 4) * 8;
    const float* p0 = whh + (size_t)(w * 512 + slice * 32 + r15) * HID + k8;
    const float* p1 = p0 + 16 * HID;
#pragma unroll
    for (int kt = 0; kt < 16; ++kt) {
      float4 a = *(const float4*)(p0 + kt * 32);
      float4 b = *(const float4*)(p0 + kt * 32 + 4);
      bw0[kt] = (v8h){(_Float16)a.x, (_Float16)a.y, (_Float16)a.z, (_Float16)a.w,
                      (_Float16)b.x, (_Float16)b.y, (_Float16)b.z, (_Float16)b.w};
      float4 c = *(const float4*)(p1 + kt * 32);
      float4 d = *(const float4*)(p1 + kt * 32 + 4);
      bw1[kt] = (v8h){(_Float16)c.x, (_Float16)c.y, (_Float16)c.z, (_Float16)c.w,
                      (_Float16)d.x, (_Float16)d.y, (_Float16)d.z, (_Float16)d.w};
    }
  }

  // ---- epilogue thread state: tid<64 owns (seq = tid>>4, cols ec0,ec0+1)
  const int eseq = tid >> 4;
  const int ec0  = (tid & 15) * 2;
  const int ej   = slice * 32 + ec0;
  float hr0 = 0.f, hr1 = 0.f;
  float br0 = 0, br1 = 0, bz0 = 0, bz1 = 0, bn0 = 0, bn1 = 0;
  int mylen = 0;
  unsigned pg0 = 0, pg1 = 0, pg2 = 0;
  if (tid < 64) {
    br0 = bhh[ej];        br1 = bhh[ej + 1];
    bz0 = bhh[ej + 512];  bz1 = bhh[ej + 513];
    bn0 = bhh[ej + 1024]; bn1 = bhh[ej + 1025];
    mylen = lens[b0 + eseq];
    const _Float16* gxr = gx + ((size_t)0 * BATCH + b0 + eseq) * G3 + ej;
    pg0 = *(const unsigned*)gxr;
    pg1 = *(const unsigned*)(gxr + 512);
    pg2 = *(const unsigned*)(gxr + 1024);
  }
  const int glen = max(max(lens[b0], lens[b0 + 1]), max(lens[b0 + 2], lens[b0 + 3]));
  __syncthreads();
  int llive = sres[0];   // sticky per-thread: 1 = poll own-XCD L2 arena

  const int arow = lane & 15;
  const int ak   = (lane >> 4) * 8;
  const _Float16* hbase = &h16[arow * 520 + ak];

  // pull-set indices for this thread: pad to exactly 6 (dups harmless)
  int ii[6]; int nn = 0;
  for (int i = tid; i < SPG * 256; i += 192) { ii[nn] = i; ++nn; }
  for (int j = nn; j < 6; ++j) ii[j] = ii[0];

  for (int t = 0; t < glen; ++t) {
    // ---- matvec: gh[seq][row] for this wave's 32 rows
    v4f acc0 = (v4f){0.f, 0.f, 0.f, 0.f};
    v4f acc1 = (v4f){0.f, 0.f, 0.f, 0.f};
#pragma unroll
    for (int kt = 0; kt < 16; ++kt) {
      v8h af = *(const v8h*)(hbase + kt * 32);
      acc0 = __builtin_amdgcn_mfma_f32_16x16x32_f16(af, bw0[kt], acc0, 0, 0, 0);
      acc1 = __builtin_amdgcn_mfma_f32_16x16x32_f16(af, bw1[kt], acc1, 0, 0, 0);
    }
    if (lane < 16) {  // lanes 0..15: reg p = seq p, col n = lane
      *(v4f*)&ghl[(w * 32 + lane) * 4]      = acc0;
      *(v4f*)&ghl[(w * 32 + 16 + lane) * 4] = acc1;
    }
    __syncthreads();   // ghl ready; all h16 MFMA reads done

    if (tid < 64) {
      const float ar0 = ghl[(0 * 32 + ec0) * 4 + eseq], ar1 = ghl[(0 * 32 + ec0 + 1) * 4 + eseq];
      const float az0 = ghl[(1 * 32 + ec0) * 4 + eseq], az1 = ghl[(1 * 32 + ec0 + 1) * 4 + eseq];
      const float an0 = ghl[(2 * 32 + ec0) * 4 + eseq], an1 = ghl[(2 * 32 + ec0 + 1) * 4 + eseq];
      union { unsigned u; _Float16 h[2]; } g0, g1, g2, pk;
      g0.u = pg0; g1.u = pg1; g2.u = pg2;
      const bool act = (t < mylen);
      if (act) {
        const float r0 = 1.f / (1.f + __expf(-((float)g0.h[0] + ar0 + br0)));
        const float z0 = 1.f / (1.f + __expf(-((float)g1.h[0] + az0 + bz0)));
        const float p0 = (float)g2.h[0] + r0 * (an0 + bn0);
        const float n0v = 1.f - 2.f / (__expf(2.f * p0) + 1.f);
        hr0 = (1.f - z0) * n0v + z0 * hr0;
        const float r1 = 1.f / (1.f + __expf(-((float)g0.h[1] + ar1 + br1)));
        const float z1 = 1.f / (1.f + __expf(-((float)g1.h[1] + az1 + bz1)));
        const float p1 = (float)g2.h[1] + r1 * (an1 + bn1);
        const float n1v = 1.f - 2.f / (__expf(2.f * p1) + 1.f);
        hr1 = (1.f - z1) * n1v + z1 * hr1;
      }
      // publish first (peers' critical path): dual publish L2 + MALL
      pk.h[0] = (_Float16)hr0; pk.h[1] = (_Float16)hr1;
      const unsigned long long pv =
          ((unsigned long long)(unsigned)(t + 1) << 32) | pk.u;
      const size_t di = (size_t)((((t + 1) & 1) * NGROUP + grp) * SPG + eseq) * 256
                        + slice * 16 + (tid & 15);
      __hip_atomic_store(hbufL + di, pv, __ATOMIC_RELAXED,
                         __HIP_MEMORY_SCOPE_WORKGROUP);   // plain -> own L2
      __hip_atomic_store(hbufA + di, pv, __ATOMIC_RELAXED,
                         __HIP_MEMORY_SCOPE_AGENT);       // MALL safety copy
      if (act) {
        float* o = out + (size_t)t * (BATCH * HID) + (size_t)(b0 + eseq) * HID + ej;
        o[0] = hr0; o[1] = hr1;
      }
      // prefetch gx for next step (off critical path; clamp in-bounds)
      const int tn = (t + 1 < glen) ? t + 1 : t;
      const _Float16* gxr = gx + ((size_t)tn * BATCH + b0 + eseq) * G3 + ej;
      pg0 = *(const unsigned*)gxr;
      pg1 = *(const unsigned*)(gxr + 512);
      pg2 = *(const unsigned*)(gxr + 1024);
    }

    // ---- tagged pull for step t+1: poll until tag >= t+1
    {
      const size_t aoff = (size_t)(((t + 1) & 1) * NGROUP + grp) * (SPG * 256);
      const unsigned want = (unsigned)(t + 1);
      unsigned pend = 0x3fu;
      if (llive) {
        // own-XCD L2 polling: plain sc0 loads (L1-bypass, L2-served, fresh)
        const unsigned long long a0 = (unsigned long long)(hbufL + aoff + ii[0]);
        const unsigned long long a1 = (unsigned long long)(hbufL + aoff + ii[1]);
        const unsigned long long a2 = (unsigned long long)(hbufL + aoff + ii[2]);
        const unsigned long long a3 = (unsigned long long)(hbufL + aoff + ii[3]);
        const unsigned long long a4 = (unsigned long long)(hbufL + aoff + ii[4]);
        const unsigned long long a5 = (unsigned long long)(hbufL + aoff + ii[5]);
        int rounds = 0;
        while (pend) {
          unsigned long long g0, g1, g2, g3, g4, g5;
          asm volatile(
              "global_load_dwordx2 %0, %6, off sc0\n\t"
              "global_load_dwordx2 %1, %7, off sc0\n\t"
              "global_load_dwordx2 %2, %8, off sc0\n\t"
              "global_load_dwordx2 %3, %9, off sc0\n\t"
              "global_load_dwordx2 %4, %10, off sc0\n\t"
              "global_load_dwordx2 %5, %11, off sc0\n\t"
              "s_waitcnt vmcnt(0)"
              : "=&v"(g0), "=&v"(g1), "=&v"(g2), "=&v"(g3), "=&v"(g4), "=&v"(g5)
              : "v"(a0), "v"(a1), "v"(a2), "v"(a3), "v"(a4), "v"(a5)
              : "memory");
#define LAND7(J, G)                                                            \
          if ((pend & (1u << J)) && (unsigned)((G) >> 32) >= want) {           \
            const int sq = ii[J] >> 8, jj = ii[J] & 255;                       \
            *(unsigned*)&h16[sq * 520 + jj * 2] = (unsigned)(G);               \
            pend &= ~(1u << J);                                               \
          }
          LAND7(0, g0) LAND7(1, g1) LAND7(2, g2)
          LAND7(3, g3) LAND7(4, g4) LAND7(5, g5)
          if (!pend) break;
          if (++rounds > 256) { llive = 0; break; }   // sticky fallback
          __builtin_amdgcn_s_sleep(1);
        }
      }
      if (pend) {
        // v2-proven agent-scope protocol (also the sticky-fallback path)
        const unsigned long long* srcA = hbufA + aoff;
        unsigned long long got[6];
        while (pend) {
#pragma unroll
          for (int j = 0; j < 6; ++j)
            if (pend & (1u << j))
              got[j] = __hip_atomic_load(srcA + ii[j], __ATOMIC_RELAXED,
                                         __HIP_MEMORY_SCOPE_AGENT);
#pragma unroll
          for (int j = 0; j < 6; ++j)
            if ((pend & (1u << j)) && (unsigned)(got[j] >> 32) >= want) {
              const int sq = ii[j] >> 8, jj = ii[j] & 255;
              *(unsigned*)&h16[sq * 520 + jj * 2] = (unsigned)got[j];
              pend &= ~(1u << j);
            }
          if (pend) __builtin_amdgcn_s_sleep(1);
        }
      }
    }
    __syncthreads();   // h16 (t+1) ready for next matvec
  }

  if (tid < 64) {
    float* hl = out + (size_t)T_STEPS * BATCH * HID + (size_t)(b0 + eseq) * HID + ej;
    hl[0] = hr0; hl[1] = hr1;
  }
}

// ---------------------------------------------------------------------------
extern "C" void kernel_launch(void* const* d_in, const int* in_sizes, int n_in,
                              void* d_out, int out_size, void* d_ws, size_t ws_size,
                              hipStream_t stream) {
  const float* x    = (const float*)d_in[0];
  const int*   lens = (const int*)d_in[1];
  const float* w_ih = (const float*)d_in[2];
  const float* w_hh = (const float*)d_in[3];
  const float* b_ih = (const float*)d_in[4];
  const float* b_hh = (const float*)d_in[5];
  float* out = (float*)d_out;

  // ws: gx f16 [65536][1536] = 192 MiB | hbufA + hbufL + xtab
  _Float16* gxbuf = (_Float16*)d_ws;
  unsigned long long* hb = (unsigned long long*)(gxbuf + (size_t)M_ROWS * G3);

  zero_hbuf<<<dim3((ZERO_U64 + 255) / 256), dim3(256), 0, stream>>>(hb);
  zero_out_tail<<<dim3(2048), dim3(256), 0, stream>>>(lens, out);
  gemm_gx<<<dim3(G3 / BN, M_ROWS / BM), dim3(256), 0, stream>>>(x, w_ih, b_ih, gxbuf);
  gru_scan7<<<dim3(NSLICE * NGROUP), dim3(192), 0, stream>>>(
      gxbuf, w_hh, lens, b_hh, out, hb);
}